// Round 10
// baseline (65.724 us; speedup 1.0000x reference)
//
#include <hip/hip_runtime.h>
#include <math.h>

#define TEMP_INV (1.0f / 0.07f)     // fixed LSE shift M (sims bounded by 1/T)
#define FIX_SCALE 35184372088832.0f // 2^45

typedef float vf4 __attribute__((ext_vector_type(4)));

__device__ __forceinline__ float wave_reduce_sum(float v) {
    #pragma unroll
    for (int off = 32; off; off >>= 1) v += __shfl_down(v, off);
    return v;
}

// fold two value-streams into one register: lanes with (lane&span) carry hi.
__device__ __forceinline__ float merge2(float lo, float hi, int span, int lane) {
    float a = lo + __shfl_xor(lo, span);
    float b = hi + __shfl_xor(hi, span);
    return (lane & span) ? b : a;
}

// monotone float->uint key: unsigned order == float order
__device__ __forceinline__ unsigned fkey(float f) {
    unsigned u = __float_as_uint(f);
    return (u & 0x80000000u) ? ~u : (u | 0x80000000u);
}

// k_pre: zero accumulators + per-row pos_sim (one row per wave).
__global__ void k_pre(const float* __restrict__ A, const float* __restrict__ P,
                      float* __restrict__ pos_sim,
                      unsigned long long* __restrict__ sum_acc,
                      unsigned* __restrict__ max_acc, int B) {
    int tid  = (int)blockIdx.x * 256 + (int)threadIdx.x;
    if (tid < B) { sum_acc[tid] = 0ULL; max_acc[tid] = 0u; }

    int wave = tid >> 6;
    int lane = threadIdx.x & 63;
    if (wave >= B) return;
    const float4 a = reinterpret_cast<const float4*>(A + (size_t)wave * 256)[lane];
    const float4 p = reinterpret_cast<const float4*>(P + (size_t)wave * 256)[lane];
    float sa = a.x * a.x + a.y * a.y + a.z * a.z + a.w * a.w;
    float sp = p.x * p.x + p.y * p.y + p.z * p.z + p.w * p.w;
    float dq = a.x * p.x + a.y * p.y + a.z * p.z + a.w * p.w;
    sa = wave_reduce_sum(sa);
    sp = wave_reduce_sum(sp);
    dq = wave_reduce_sum(dq);
    if (lane == 0) {
        float ia = 1.0f / fmaxf(sqrtf(sa), 1e-12f);
        float ip = 1.0f / fmaxf(sqrtf(sp), 1e-12f);
        pos_sim[wave] = dq * ia * ip * TEMP_INV;
    }
}

// k_neg: grid-strided 4-row chunks; self-contained sim (anchor norm computed
// in-loop); per-row fixed-point atomic accumulation (order-independent).
__global__ void k_neg(const float* __restrict__ A, const float* __restrict__ Ng,
                      const int* __restrict__ idx,
                      unsigned long long* __restrict__ sum_acc,
                      unsigned* __restrict__ max_acc, int N) {
    const int lane = threadIdx.x & 63;
    const int wave = ((int)blockIdx.x * 256 + (int)threadIdx.x) >> 6;
    const int nwaves = (int)gridDim.x * 4;
    const int nchunks = N >> 2;
    const float4* A4 = reinterpret_cast<const float4*>(A);

    for (int chunk = wave; chunk < nchunks; chunk += nwaves) {
        int j0 = chunk << 2;
        int4 bi = *reinterpret_cast<const int4*>(idx + j0);
        int b0 = __builtin_amdgcn_readfirstlane(bi.x);
        int b1 = __builtin_amdgcn_readfirstlane(bi.y);
        int b2 = __builtin_amdgcn_readfirstlane(bi.z);
        int b3 = __builtin_amdgcn_readfirstlane(bi.w);

        const vf4 n0 = __builtin_nontemporal_load(
            reinterpret_cast<const vf4*>(Ng + (size_t)j0 * 256) + lane);
        const vf4 n1 = __builtin_nontemporal_load(
            reinterpret_cast<const vf4*>(Ng + (size_t)(j0 + 1) * 256) + lane);
        const vf4 n2 = __builtin_nontemporal_load(
            reinterpret_cast<const vf4*>(Ng + (size_t)(j0 + 2) * 256) + lane);
        const vf4 n3 = __builtin_nontemporal_load(
            reinterpret_cast<const vf4*>(Ng + (size_t)(j0 + 3) * 256) + lane);

        float4 a0 = A4[(size_t)b0 * 64 + lane];
        float4 a1, a2, a3;
        if (b3 == b0) {            // wave-uniform branch; common (avg seg = 32)
            a1 = a0; a2 = a0; a3 = a0;
        } else {
            a1 = A4[(size_t)b1 * 64 + lane];
            a2 = A4[(size_t)b2 * 64 + lane];
            a3 = A4[(size_t)b3 * 64 + lane];
        }

        float sn0 = n0.x*n0.x + n0.y*n0.y + n0.z*n0.z + n0.w*n0.w;
        float sn1 = n1.x*n1.x + n1.y*n1.y + n1.z*n1.z + n1.w*n1.w;
        float sn2 = n2.x*n2.x + n2.y*n2.y + n2.z*n2.z + n2.w*n2.w;
        float sn3 = n3.x*n3.x + n3.y*n3.y + n3.z*n3.z + n3.w*n3.w;
        float dp0 = a0.x*n0.x + a0.y*n0.y + a0.z*n0.z + a0.w*n0.w;
        float dp1 = a1.x*n1.x + a1.y*n1.y + a1.z*n1.z + a1.w*n1.w;
        float dp2 = a2.x*n2.x + a2.y*n2.y + a2.z*n2.z + a2.w*n2.w;
        float dp3 = a3.x*n3.x + a3.y*n3.y + a3.z*n3.z + a3.w*n3.w;
        float sa0 = a0.x*a0.x + a0.y*a0.y + a0.z*a0.z + a0.w*a0.w;
        float sa1 = a1.x*a1.x + a1.y*a1.y + a1.z*a1.z + a1.w*a1.w;
        float sa2 = a2.x*a2.x + a2.y*a2.y + a2.z*a2.z + a2.w*a2.w;
        float sa3 = a3.x*a3.x + a3.y*a3.y + a3.z*a3.z + a3.w*a3.w;

        // 12-value fold. After span-16: lane-group 16r holds {sn_r, dp_r, sa_r}.
        float v0 = merge2(sn0, sn2, 32, lane);
        float v1 = merge2(dp0, dp2, 32, lane);
        float v2 = merge2(sn1, sn3, 32, lane);
        float v3 = merge2(dp1, dp3, 32, lane);
        float v4 = merge2(sa0, sa2, 32, lane);
        float v5 = merge2(sa1, sa3, 32, lane);
        float m0 = merge2(v0, v2, 16, lane);   // sn_r partials
        float m1 = merge2(v1, v3, 16, lane);   // dp_r partials
        float m2 = merge2(v4, v5, 16, lane);   // sa_r partials
        float f  = merge2(m0, m1, 8, lane);    // [16r,16r+8): sn_r, [+8,+16): dp_r
        f += __shfl_xor(f, 4);
        f += __shfl_xor(f, 2);
        f += __shfl_xor(f, 1);
        float g = m2;                           // sa_r, complete over 16-group
        g += __shfl_xor(g, 8);
        g += __shfl_xor(g, 4);
        g += __shfl_xor(g, 2);
        g += __shfl_xor(g, 1);

        float fdp = __shfl_down(f, 8);          // lane 16r: dp_r
        if ((lane & 15) == 0) {
            int r = lane >> 4;
            int bb = (r == 0) ? b0 : (r == 1) ? b1 : (r == 2) ? b2 : b3;
            float inv_n = 1.0f / fmaxf(sqrtf(f), 1e-12f);
            float inv_a = 1.0f / fmaxf(sqrtf(g), 1e-12f);
            float t = fdp * inv_n * inv_a * TEMP_INV;
            float e = expf(t - TEMP_INV);       // in [3.8e-13, ~1]
            unsigned long long q = (unsigned long long)(e * FIX_SCALE);
            atomicAdd(&sum_acc[bb], q);
            atomicMax(&max_acc[bb], fkey(t));
        }
    }
}

// k_final: 1 block, fixed-order deterministic reduce -> out[0], out[1].
__global__ __launch_bounds__(1024)
void k_final(const float* __restrict__ pos_sim,
             const unsigned long long* __restrict__ sum_acc,
             const unsigned* __restrict__ max_acc,
             float* __restrict__ out, int B) {
    __shared__ float sl[16];
    __shared__ float sc[16];
    int tid = (int)threadIdx.x, lane = tid & 63, wid = tid >> 6;  // 16 waves
    float l = 0.0f, c = 0.0f;
    for (int b = tid; b < B; b += 1024) {
        unsigned long long sf = sum_acc[b];
        if (sf == 0ULL) continue;               // empty segment: skipped
        float ps = pos_sim[b];
        float se_neg = (float)sf * (1.0f / FIX_SCALE);
        l += -ps + TEMP_INV + logf(se_neg + expf(ps - TEMP_INV));
        c += (fkey(ps) > max_acc[b]) ? 1.0f : 0.0f;
    }
    l = wave_reduce_sum(l);
    c = wave_reduce_sum(c);
    if (lane == 0) { sl[wid] = l; sc[wid] = c; }
    __syncthreads();
    if (wid == 0) {
        float lv = (lane < 16) ? sl[lane] : 0.0f;
        float cv = (lane < 16) ? sc[lane] : 0.0f;
        lv = wave_reduce_sum(lv);
        cv = wave_reduce_sum(cv);
        if (lane == 0) {
            out[0] = lv / (float)B;
            out[1] = cv / (float)B;
        }
    }
}

extern "C" void kernel_launch(void* const* d_in, const int* in_sizes, int n_in,
                              void* d_out, int out_size, void* d_ws, size_t ws_size,
                              hipStream_t stream) {
    const float* anchor    = (const float*)d_in[0];
    const float* positive  = (const float*)d_in[1];
    const float* negatives = (const float*)d_in[2];
    const int*   idx       = (const int*)d_in[3];

    const int D = 256;
    const int B = in_sizes[0] / D;   // 4096
    const int N = in_sizes[2] / D;   // 131072

    // workspace layout (8B-aligned base): sum_acc u64[B], max_acc u32[B],
    // pos_sim f32[B]
    unsigned long long* sum_acc = (unsigned long long*)d_ws;
    unsigned* max_acc = (unsigned*)(sum_acc + B);
    float*    pos_sim = (float*)(max_acc + B);

    float* out = (float*)d_out;

    k_pre<<<(B * 64 + 255) / 256, 256, 0, stream>>>(anchor, positive, pos_sim,
                                                    sum_acc, max_acc, B);

    k_neg<<<2048, 256, 0, stream>>>(anchor, negatives, idx, sum_acc, max_acc, N);

    k_final<<<1, 1024, 0, stream>>>(pos_sim, sum_acc, max_acc, out, B);
}

// Round 11
// 35.610 us; speedup vs baseline: 1.8456x; 1.8456x over previous
//
#include <hip/hip_runtime.h>
#include <math.h>

#define TEMP_INV (1.0f / 0.07f)   // also the fixed LSE shift M (sims bounded by 1/T)

typedef float vf4 __attribute__((ext_vector_type(4)));

#define DOT4(a, n) ((a).x*(n).x + (a).y*(n).y + (a).z*(n).z + (a).w*(n).w)

__device__ __forceinline__ float wave_reduce_sum(float v) {
    #pragma unroll
    for (int off = 32; off; off >>= 1) v += __shfl_down(v, off);
    return v;
}

__device__ __forceinline__ float wave_reduce_max(float v) {
    #pragma unroll
    for (int off = 32; off; off >>= 1) v = fmaxf(v, __shfl_down(v, off));
    return v;
}

// fold two value-streams into one register: lanes with (lane&span) carry hi.
__device__ __forceinline__ float merge2(float lo, float hi, int span, int lane) {
    float a = lo + __shfl_xor(lo, span);
    float b = hi + __shfl_xor(hi, span);
    return (lane & span) ? b : a;
}

// Persistent kernel: (1) one anchor/positive row per wave, (2) seg_start fill,
// (3) grid-strided negative chunks, 8 rows / 8KB per iteration.
__global__ void k_main(const float* __restrict__ A, const float* __restrict__ P,
                       const float* __restrict__ Ng, const int* __restrict__ idx,
                       float* __restrict__ inv_na, float* __restrict__ pos_sim,
                       float* __restrict__ raw, int* __restrict__ seg_start,
                       int B, int N) {
    const int bid  = (int)blockIdx.x;
    const int wib  = threadIdx.x >> 6;
    const int lane = threadIdx.x & 63;
    const int wave = bid * 4 + wib;
    const int nwaves = (int)gridDim.x * 4;

    // ---- Phase 1: row stats (one row per wave; B <= nwaves) ----
    if (wave < B) {
        int b = wave;
        const float4 a = reinterpret_cast<const float4*>(A + (size_t)b * 256)[lane];
        const float4 p = reinterpret_cast<const float4*>(P + (size_t)b * 256)[lane];
        float sa = DOT4(a, a);
        float sp = DOT4(p, p);
        float dq = DOT4(a, p);
        sa = wave_reduce_sum(sa);
        sp = wave_reduce_sum(sp);
        dq = wave_reduce_sum(dq);
        if (lane == 0) {
            float ia = 1.0f / fmaxf(sqrtf(sa), 1e-12f);
            float ip = 1.0f / fmaxf(sqrtf(sp), 1e-12f);
            inv_na[b]  = ia;
            pos_sim[b] = dq * ia * ip * TEMP_INV;
        }
    }

    // ---- Phase 2: seg_start[v] = lower_bound(idx, v), v in [0,B] ----
    {
        int t = bid * 256 + (int)threadIdx.x;
        int stride = (int)gridDim.x * 256;
        for (int j = t; j <= N; j += stride) {
            if (j == 0) {
                int c = idx[0];
                for (int v = 0; v <= c; ++v) seg_start[v] = 0;
            } else if (j < N) {
                int prev = idx[j - 1], cur = idx[j];
                for (int v = prev + 1; v <= cur; ++v) seg_start[v] = j;
            } else {
                int prev = idx[N - 1];
                for (int v = prev + 1; v <= B; ++v) seg_start[v] = N;
            }
        }
    }

    // ---- Phase 3: negative sims, 8 rows per iteration ----
    const int nchunks = N >> 3;
    const float4* A4 = reinterpret_cast<const float4*>(A);
    for (int chunk = wave; chunk < nchunks; chunk += nwaves) {
        int j0 = chunk << 3;
        int4 biA = *reinterpret_cast<const int4*>(idx + j0);
        int4 biB = *reinterpret_cast<const int4*>(idx + j0 + 4);
        int b0 = __builtin_amdgcn_readfirstlane(biA.x);
        int b1 = __builtin_amdgcn_readfirstlane(biA.y);
        int b2 = __builtin_amdgcn_readfirstlane(biA.z);
        int b3 = __builtin_amdgcn_readfirstlane(biA.w);
        int b4 = __builtin_amdgcn_readfirstlane(biB.x);
        int b5 = __builtin_amdgcn_readfirstlane(biB.y);
        int b6 = __builtin_amdgcn_readfirstlane(biB.z);
        int b7 = __builtin_amdgcn_readfirstlane(biB.w);

        const vf4 n0 = __builtin_nontemporal_load(
            reinterpret_cast<const vf4*>(Ng + (size_t)(j0 + 0) * 256) + lane);
        const vf4 n1 = __builtin_nontemporal_load(
            reinterpret_cast<const vf4*>(Ng + (size_t)(j0 + 1) * 256) + lane);
        const vf4 n2 = __builtin_nontemporal_load(
            reinterpret_cast<const vf4*>(Ng + (size_t)(j0 + 2) * 256) + lane);
        const vf4 n3 = __builtin_nontemporal_load(
            reinterpret_cast<const vf4*>(Ng + (size_t)(j0 + 3) * 256) + lane);
        const vf4 n4 = __builtin_nontemporal_load(
            reinterpret_cast<const vf4*>(Ng + (size_t)(j0 + 4) * 256) + lane);
        const vf4 n5 = __builtin_nontemporal_load(
            reinterpret_cast<const vf4*>(Ng + (size_t)(j0 + 5) * 256) + lane);
        const vf4 n6 = __builtin_nontemporal_load(
            reinterpret_cast<const vf4*>(Ng + (size_t)(j0 + 6) * 256) + lane);
        const vf4 n7 = __builtin_nontemporal_load(
            reinterpret_cast<const vf4*>(Ng + (size_t)(j0 + 7) * 256) + lane);

        float sn0 = DOT4(n0, n0), sn1 = DOT4(n1, n1);
        float sn2 = DOT4(n2, n2), sn3 = DOT4(n3, n3);
        float sn4 = DOT4(n4, n4), sn5 = DOT4(n5, n5);
        float sn6 = DOT4(n6, n6), sn7 = DOT4(n7, n7);

        float dp0, dp1, dp2, dp3, dp4, dp5, dp6, dp7;
        if (b7 == b0) {            // wave-uniform branch; common (avg seg = 32)
            float4 a = A4[(size_t)b0 * 64 + lane];
            dp0 = DOT4(a, n0); dp1 = DOT4(a, n1);
            dp2 = DOT4(a, n2); dp3 = DOT4(a, n3);
            dp4 = DOT4(a, n4); dp5 = DOT4(a, n5);
            dp6 = DOT4(a, n6); dp7 = DOT4(a, n7);
        } else {
            { float4 a = A4[(size_t)b0 * 64 + lane]; dp0 = DOT4(a, n0); }
            { float4 a = A4[(size_t)b1 * 64 + lane]; dp1 = DOT4(a, n1); }
            { float4 a = A4[(size_t)b2 * 64 + lane]; dp2 = DOT4(a, n2); }
            { float4 a = A4[(size_t)b3 * 64 + lane]; dp3 = DOT4(a, n3); }
            { float4 a = A4[(size_t)b4 * 64 + lane]; dp4 = DOT4(a, n4); }
            { float4 a = A4[(size_t)b5 * 64 + lane]; dp5 = DOT4(a, n5); }
            { float4 a = A4[(size_t)b6 * 64 + lane]; dp6 = DOT4(a, n6); }
            { float4 a = A4[(size_t)b7 * 64 + lane]; dp7 = DOT4(a, n7); }
        }

        // 16-value fold: val[2r]=sn_r, val[2r+1]=dp_r.
        // Selection bits: lane&32 -> +8, &16 -> +4, &8 -> +2, &4 -> +1.
        // Final: lane 4v..4v+3 holds value v = lane>>2, i.e. sn_r at lane 8r,
        // dp_r at lane 8r+4.
        float m0 = merge2(sn0, sn4, 32, lane);  // val0 / val8
        float m1 = merge2(dp0, dp4, 32, lane);  // val1 / val9
        float m2 = merge2(sn1, sn5, 32, lane);  // val2 / val10
        float m3 = merge2(dp1, dp5, 32, lane);  // val3 / val11
        float m4 = merge2(sn2, sn6, 32, lane);  // val4 / val12
        float m5 = merge2(dp2, dp6, 32, lane);  // val5 / val13
        float m6 = merge2(sn3, sn7, 32, lane);  // val6 / val14
        float m7 = merge2(dp3, dp7, 32, lane);  // val7 / val15
        float p0 = merge2(m0, m4, 16, lane);
        float p1 = merge2(m1, m5, 16, lane);
        float p2 = merge2(m2, m6, 16, lane);
        float p3 = merge2(m3, m7, 16, lane);
        float q0 = merge2(p0, p2, 8, lane);
        float q1 = merge2(p1, p3, 8, lane);
        float f  = merge2(q0, q1, 4, lane);
        f += __shfl_xor(f, 2);
        f += __shfl_xor(f, 1);

        float fdp = __shfl_down(f, 4);          // lane 8r receives dp_r
        if ((lane & 7) == 0) {
            int r = lane >> 3;
            raw[j0 + r] = fdp * (1.0f / fmaxf(sqrtf(f), 1e-12f)) * TEMP_INV;
        }
    }
}

// One wave per batch row (4 rows per 256-thread block): fixed-M single-pass LSE.
__global__ void k_seg(const float* __restrict__ raw, const int* __restrict__ seg_start,
                      const float* __restrict__ inv_na, const float* __restrict__ pos_sim,
                      float* __restrict__ loss_i, float* __restrict__ corr, int B) {
    int b = (int)blockIdx.x * 4 + (threadIdx.x >> 6);
    int lane = threadIdx.x & 63;
    if (b >= B) return;

    int s = seg_start[b];
    int e = seg_start[b + 1];

    float ps = pos_sim[b];
    float ia = inv_na[b];

    float l_val = 0.0f, c_val = 0.0f;
    if (e > s) {
        const float M = TEMP_INV;
        float mx = -INFINITY, se = 0.0f;
        for (int j = s + lane; j < e; j += 64) {
            float t = raw[j] * ia;
            mx = fmaxf(mx, t);
            se += expf(t - M);
        }
        mx = wave_reduce_max(mx);
        se = wave_reduce_sum(se);
        mx = __shfl(mx, 0);
        se = __shfl(se, 0);
        l_val = -ps + M + logf(se + expf(ps - M));
        c_val = (ps > mx) ? 1.0f : 0.0f;
    }
    if (lane == 0) { loss_i[b] = l_val; corr[b] = c_val; }
}

// Single-block deterministic reduce -> out[0]=loss, out[1]=accuracy
__global__ __launch_bounds__(1024)
void k_final(const float* __restrict__ loss_i, const float* __restrict__ corr,
             float* __restrict__ out, int B) {
    __shared__ float sl[16];
    __shared__ float sc[16];
    int tid = (int)threadIdx.x, lane = tid & 63, wid = tid >> 6;  // 16 waves
    float l = 0.0f, c = 0.0f;
    for (int i = tid; i < B; i += 1024) { l += loss_i[i]; c += corr[i]; }
    l = wave_reduce_sum(l);
    c = wave_reduce_sum(c);
    if (lane == 0) { sl[wid] = l; sc[wid] = c; }
    __syncthreads();
    if (wid == 0) {
        float lv = (lane < 16) ? sl[lane] : 0.0f;
        float cv = (lane < 16) ? sc[lane] : 0.0f;
        lv = wave_reduce_sum(lv);
        cv = wave_reduce_sum(cv);
        if (lane == 0) {
            out[0] = lv / (float)B;
            out[1] = cv / (float)B;
        }
    }
}

extern "C" void kernel_launch(void* const* d_in, const int* in_sizes, int n_in,
                              void* d_out, int out_size, void* d_ws, size_t ws_size,
                              hipStream_t stream) {
    const float* anchor    = (const float*)d_in[0];
    const float* positive  = (const float*)d_in[1];
    const float* negatives = (const float*)d_in[2];
    const int*   idx       = (const int*)d_in[3];

    const int D = 256;
    const int B = in_sizes[0] / D;   // 4096
    const int N = in_sizes[2] / D;   // 131072

    float* ws        = (float*)d_ws;
    float* raw       = ws;                      // N
    float* inv_na    = ws + N;                  // B
    float* pos_sim   = ws + N + B;              // B
    float* loss_i    = ws + N + 2 * B;          // B
    float* corr      = ws + N + 3 * B;          // B
    int*   seg_start = (int*)(ws + N + 4 * B);  // B + 1

    float* out = (float*)d_out;

    // 2048 blocks x 256 threads = machine fill; 8192 waves, 16384 chunks -> 2 iters/wave
    k_main<<<2048, 256, 0, stream>>>(anchor, positive, negatives, idx,
                                     inv_na, pos_sim, raw, seg_start, B, N);

    k_seg<<<(B + 3) / 4, 256, 0, stream>>>(raw, seg_start, inv_na, pos_sim,
                                           loss_i, corr, B);

    k_final<<<1, 1024, 0, stream>>>(loss_i, corr, out, B);
}

// Round 12
// 34.051 us; speedup vs baseline: 1.9302x; 1.0458x over previous
//
#include <hip/hip_runtime.h>
#include <math.h>

#define TEMP_INV (1.0f / 0.07f)   // also the fixed LSE shift M (sims bounded by 1/T)

typedef float vf4 __attribute__((ext_vector_type(4)));

#define DOT4(a, n) ((a).x*(n).x + (a).y*(n).y + (a).z*(n).z + (a).w*(n).w)

__device__ __forceinline__ float wave_reduce_sum(float v) {
    #pragma unroll
    for (int off = 32; off; off >>= 1) v += __shfl_down(v, off);
    return v;
}

__device__ __forceinline__ float wave_reduce_max(float v) {
    #pragma unroll
    for (int off = 32; off; off >>= 1) v = fmaxf(v, __shfl_down(v, off));
    return v;
}

// fold two value-streams into one register: lanes with (lane&span) carry hi.
__device__ __forceinline__ float merge2(float lo, float hi, int span, int lane) {
    float a = lo + __shfl_xor(lo, span);
    float b = hi + __shfl_xor(hi, span);
    return (lane & span) ? b : a;
}

// Persistent kernel, <=64 VGPR target (8 waves/SIMD): (1) one anchor/positive
// row per wave, (2) seg_start fill, (3) grid-strided negative chunks
// (4 rows / 4KB per iter, anchors loaded unconditionally & consumed row-by-row).
__global__ __launch_bounds__(256, 8)
void k_main(const float* __restrict__ A, const float* __restrict__ P,
            const float* __restrict__ Ng, const int* __restrict__ idx,
            float* __restrict__ inv_na, float* __restrict__ pos_sim,
            float* __restrict__ raw, int* __restrict__ seg_start,
            int B, int N) {
    const int bid  = (int)blockIdx.x;
    const int wib  = threadIdx.x >> 6;
    const int lane = threadIdx.x & 63;
    const int wave = bid * 4 + wib;
    const int nwaves = (int)gridDim.x * 4;

    // ---- Phase 1: row stats (one row per wave; B <= nwaves) ----
    if (wave < B) {
        int b = wave;
        const float4 a = reinterpret_cast<const float4*>(A + (size_t)b * 256)[lane];
        const float4 p = reinterpret_cast<const float4*>(P + (size_t)b * 256)[lane];
        float sa = DOT4(a, a);
        float sp = DOT4(p, p);
        float dq = DOT4(a, p);
        sa = wave_reduce_sum(sa);
        sp = wave_reduce_sum(sp);
        dq = wave_reduce_sum(dq);
        if (lane == 0) {
            float ia = 1.0f / fmaxf(sqrtf(sa), 1e-12f);
            float ip = 1.0f / fmaxf(sqrtf(sp), 1e-12f);
            inv_na[b]  = ia;
            pos_sim[b] = dq * ia * ip * TEMP_INV;
        }
    }

    // ---- Phase 2: seg_start[v] = lower_bound(idx, v), v in [0,B] ----
    {
        int t = bid * 256 + (int)threadIdx.x;
        int stride = (int)gridDim.x * 256;
        for (int j = t; j <= N; j += stride) {
            if (j == 0) {
                int c = idx[0];
                for (int v = 0; v <= c; ++v) seg_start[v] = 0;
            } else if (j < N) {
                int prev = idx[j - 1], cur = idx[j];
                for (int v = prev + 1; v <= cur; ++v) seg_start[v] = j;
            } else {
                int prev = idx[N - 1];
                for (int v = prev + 1; v <= B; ++v) seg_start[v] = N;
            }
        }
    }

    // ---- Phase 3: negative sims, 4 rows per iteration ----
    const int nchunks = N >> 2;
    const float4* A4 = reinterpret_cast<const float4*>(A);
    for (int chunk = wave; chunk < nchunks; chunk += nwaves) {
        int j0 = chunk << 2;
        int4 bi = *reinterpret_cast<const int4*>(idx + j0);
        int b0 = __builtin_amdgcn_readfirstlane(bi.x);
        int b1 = __builtin_amdgcn_readfirstlane(bi.y);
        int b2 = __builtin_amdgcn_readfirstlane(bi.z);
        int b3 = __builtin_amdgcn_readfirstlane(bi.w);

        const vf4 n0 = __builtin_nontemporal_load(
            reinterpret_cast<const vf4*>(Ng + (size_t)(j0 + 0) * 256) + lane);
        const vf4 n1 = __builtin_nontemporal_load(
            reinterpret_cast<const vf4*>(Ng + (size_t)(j0 + 1) * 256) + lane);
        const vf4 n2 = __builtin_nontemporal_load(
            reinterpret_cast<const vf4*>(Ng + (size_t)(j0 + 2) * 256) + lane);
        const vf4 n3 = __builtin_nontemporal_load(
            reinterpret_cast<const vf4*>(Ng + (size_t)(j0 + 3) * 256) + lane);

        // Unconditional anchor loads (duplicates hit L1); consumed row-by-row
        // to keep the live set under 64 VGPR.
        const float4 a0 = A4[(size_t)b0 * 64 + lane];
        const float4 a1 = A4[(size_t)b1 * 64 + lane];
        const float4 a2 = A4[(size_t)b2 * 64 + lane];
        const float4 a3 = A4[(size_t)b3 * 64 + lane];

        float sn0 = DOT4(n0, n0);
        float dp0 = DOT4(a0, n0);
        float sn1 = DOT4(n1, n1);
        float dp1 = DOT4(a1, n1);
        float sn2 = DOT4(n2, n2);
        float dp2 = DOT4(a2, n2);
        float sn3 = DOT4(n3, n3);
        float dp3 = DOT4(a3, n3);

        // 8-value fold: 17 shuffles. sn_r -> lane 16r, dp_r -> lane 16r+8.
        float nv0 = merge2(sn0, sn2, 32, lane);
        float nv1 = merge2(dp0, dp2, 32, lane);
        float nv2 = merge2(sn1, sn3, 32, lane);
        float nv3 = merge2(dp1, dp3, 32, lane);
        float m0  = merge2(nv0, nv2, 16, lane);
        float m1  = merge2(nv1, nv3, 16, lane);
        float f   = merge2(m0,  m1,   8, lane);
        f += __shfl_xor(f, 4);
        f += __shfl_xor(f, 2);
        f += __shfl_xor(f, 1);

        float fdp = __shfl_down(f, 8);   // lane 16r receives dp_r
        if ((lane & 15) == 0) {
            int r = lane >> 4;
            raw[j0 + r] = fdp * (1.0f / fmaxf(sqrtf(f), 1e-12f)) * TEMP_INV;
        }
    }
}

// One wave per batch row (4 rows per 256-thread block): fixed-M single-pass LSE.
__global__ void k_seg(const float* __restrict__ raw, const int* __restrict__ seg_start,
                      const float* __restrict__ inv_na, const float* __restrict__ pos_sim,
                      float* __restrict__ loss_i, float* __restrict__ corr, int B) {
    int b = (int)blockIdx.x * 4 + (threadIdx.x >> 6);
    int lane = threadIdx.x & 63;
    if (b >= B) return;

    int s = seg_start[b];
    int e = seg_start[b + 1];

    float ps = pos_sim[b];
    float ia = inv_na[b];

    float l_val = 0.0f, c_val = 0.0f;
    if (e > s) {
        const float M = TEMP_INV;
        float mx = -INFINITY, se = 0.0f;
        for (int j = s + lane; j < e; j += 64) {
            float t = raw[j] * ia;
            mx = fmaxf(mx, t);
            se += expf(t - M);
        }
        mx = wave_reduce_max(mx);
        se = wave_reduce_sum(se);
        mx = __shfl(mx, 0);
        se = __shfl(se, 0);
        l_val = -ps + M + logf(se + expf(ps - M));
        c_val = (ps > mx) ? 1.0f : 0.0f;
    }
    if (lane == 0) { loss_i[b] = l_val; corr[b] = c_val; }
}

// Single-block deterministic reduce -> out[0]=loss, out[1]=accuracy
__global__ __launch_bounds__(1024)
void k_final(const float* __restrict__ loss_i, const float* __restrict__ corr,
             float* __restrict__ out, int B) {
    __shared__ float sl[16];
    __shared__ float sc[16];
    int tid = (int)threadIdx.x, lane = tid & 63, wid = tid >> 6;  // 16 waves
    float l = 0.0f, c = 0.0f;
    for (int i = tid; i < B; i += 1024) { l += loss_i[i]; c += corr[i]; }
    l = wave_reduce_sum(l);
    c = wave_reduce_sum(c);
    if (lane == 0) { sl[wid] = l; sc[wid] = c; }
    __syncthreads();
    if (wid == 0) {
        float lv = (lane < 16) ? sl[lane] : 0.0f;
        float cv = (lane < 16) ? sc[lane] : 0.0f;
        lv = wave_reduce_sum(lv);
        cv = wave_reduce_sum(cv);
        if (lane == 0) {
            out[0] = lv / (float)B;
            out[1] = cv / (float)B;
        }
    }
}

extern "C" void kernel_launch(void* const* d_in, const int* in_sizes, int n_in,
                              void* d_out, int out_size, void* d_ws, size_t ws_size,
                              hipStream_t stream) {
    const float* anchor    = (const float*)d_in[0];
    const float* positive  = (const float*)d_in[1];
    const float* negatives = (const float*)d_in[2];
    const int*   idx       = (const int*)d_in[3];

    const int D = 256;
    const int B = in_sizes[0] / D;   // 4096
    const int N = in_sizes[2] / D;   // 131072

    float* ws        = (float*)d_ws;
    float* raw       = ws;                      // N
    float* inv_na    = ws + N;                  // B
    float* pos_sim   = ws + N + B;              // B
    float* loss_i    = ws + N + 2 * B;          // B
    float* corr      = ws + N + 3 * B;          // B
    int*   seg_start = (int*)(ws + N + 4 * B);  // B + 1

    float* out = (float*)d_out;

    // 2048 blocks x 256 threads; with <=64 VGPR all 8 blocks/CU are resident.
    k_main<<<2048, 256, 0, stream>>>(anchor, positive, negatives, idx,
                                     inv_na, pos_sim, raw, seg_start, B, N);

    k_seg<<<(B + 3) / 4, 256, 0, stream>>>(raw, seg_start, inv_na, pos_sim,
                                           loss_i, corr, B);

    k_final<<<1, 1024, 0, stream>>>(loss_i, corr, out, B);
}